// Round 14
// baseline (689.560 us; speedup 1.0000x reference)
//
#include <hip/hip_runtime.h>

#define DEV __device__ __forceinline__

typedef __attribute__((ext_vector_type(8))) short short8;
typedef __attribute__((ext_vector_type(4))) float f32x4;

// ---------- helpers ----------
DEV unsigned short f2bf(float f) {
  unsigned u = __builtin_bit_cast(unsigned, f);
  u += 0x7fff + ((u >> 16) & 1);   // RNE
  return (unsigned short)(u >> 16);
}

DEV void gload_lds16(const void* g, void* l) {
  __builtin_amdgcn_global_load_lds(
      (const __attribute__((address_space(1))) void*)g,
      (__attribute__((address_space(3))) void*)l, 16, 0, 0);
}

#if __has_builtin(__builtin_amdgcn_exp2f)
#define EXP2F(x) __builtin_amdgcn_exp2f(x)
#else
#define EXP2F(x) exp2f(x)
#endif

#define LOG2E 1.4426950408889634f
#define QSCALE (0.125f * LOG2E)   // folded into Q projection epilogue
#define MFMA16(a, b, c) __builtin_amdgcn_mfma_f32_16x16x32_bf16((a), (b), (c), 0, 0, 0)

// ---------- fp32 -> bf16 conversion ----------
__global__ void cvt_f32_bf16(const float* __restrict__ in, unsigned short* __restrict__ out, int n4) {
  int i = blockIdx.x * blockDim.x + threadIdx.x;
  int stride = gridDim.x * blockDim.x;
  for (; i < n4; i += stride) {
    float4 v = ((const float4*)in)[i];
    ushort4 o;
    o.x = f2bf(v.x); o.y = f2bf(v.y); o.z = f2bf(v.z); o.w = f2bf(v.w);
    ((ushort4*)out)[i] = o;
  }
}

// all 4 weight matrices (1M elems each) in one launch
__global__ void cvt_w4(const float* __restrict__ w0, const float* __restrict__ w1,
                       const float* __restrict__ w2, const float* __restrict__ w3,
                       unsigned short* __restrict__ o0, unsigned short* __restrict__ o1,
                       unsigned short* __restrict__ o2, unsigned short* __restrict__ o3) {
  int i = blockIdx.x * blockDim.x + threadIdx.x;   // 0 .. 4*262144
  int sel = i >> 18, j = i & 0x3ffff;
  const float* in = sel == 0 ? w0 : sel == 1 ? w1 : sel == 2 ? w2 : w3;
  unsigned short* out = sel == 0 ? o0 : sel == 1 ? o1 : sel == 2 ? o2 : o3;
  float4 v = ((const float4*)in)[j];
  ushort4 o;
  o.x = f2bf(v.x); o.y = f2bf(v.y); o.z = f2bf(v.z); o.w = f2bf(v.w);
  ((ushort4*)out)[j] = o;
}

// ---------- GEMM core (R10-exact, best measured): C[m,n] = sum_k A[m,k]*B[n,k] ----------
#define GK 1024
template <int MODE>  // 0: bf16 rowmajor; 1: bf16 Vt layout; 2: fp32 rowmajor; 3: bf16 rowmajor * QSCALE
DEV void gemm_body(const unsigned short* A, const unsigned short* Bw, void* Cout,
                   int bx, int by) {
  __shared__ unsigned short Ash[128 * 32];
  __shared__ unsigned short Bsh[128 * 32];
  const int tid = threadIdx.x;
  const int lane = tid & 63;
  const int w = tid >> 6;
  const int wm = w >> 1, wn = w & 1;
  const int l15 = lane & 15, l4 = lane >> 4;
  const int row0 = by * 128;
  const int col0 = bx * 128;

  f32x4 acc[4][4] = {};

  for (int kt = 0; kt < GK; kt += 32) {
    __syncthreads();
#pragma unroll
    for (int c = 0; c < 2; ++c) {
      int o = c * 4096 + tid * 16;              // linear byte offset in 8KB tile
      int ldsoff = c * 4096 + w * 1024;         // wave-uniform LDS base
      int row = o >> 6, colb = o & 63;
      gload_lds16((const char*)A + (size_t)(row0 + row) * 2048 + kt * 2 + colb,
                  (char*)Ash + ldsoff);
      gload_lds16((const char*)Bw + (size_t)(col0 + row) * 2048 + kt * 2 + colb,
                  (char*)Bsh + ldsoff);
    }
    __syncthreads();
    short8 af[4], bf[4];
#pragma unroll
    for (int m = 0; m < 4; ++m)
      af[m] = *(const short8*)((const char*)Ash + (wm * 64 + m * 16 + l15) * 64 + l4 * 16);
#pragma unroll
    for (int n = 0; n < 4; ++n)
      bf[n] = *(const short8*)((const char*)Bsh + (wn * 64 + n * 16 + l15) * 64 + l4 * 16);
#pragma unroll
    for (int m = 0; m < 4; ++m)
#pragma unroll
      for (int n = 0; n < 4; ++n)
        acc[m][n] = MFMA16(af[m], bf[n], acc[m][n]);
  }

#pragma unroll
  for (int m = 0; m < 4; ++m)
#pragma unroll
    for (int n = 0; n < 4; ++n)
#pragma unroll
      for (int r = 0; r < 4; ++r) {
        int mrow = row0 + wm * 64 + m * 16 + l4 * 4 + r;   // C/D: row=(lane>>4)*4+reg
        int ncol = col0 + wn * 64 + n * 16 + l15;          //      col=lane&15
        float v = acc[m][n][r];
        if (MODE == 0) {
          ((unsigned short*)Cout)[(size_t)mrow * 1024 + ncol] = f2bf(v);
        } else if (MODE == 1) {
          int b = mrow >> 11, s = mrow & 2047, h = ncol >> 6, d = ncol & 63;
          ((unsigned short*)Cout)[((size_t)((b * 16 + h) * 64 + d)) * 2048 + s] = f2bf(v);
        } else if (MODE == 2) {
          ((float*)Cout)[(size_t)mrow * 1024 + ncol] = v;
        } else {
          ((unsigned short*)Cout)[(size_t)mrow * 1024 + ncol] = f2bf(v * QSCALE);
        }
      }
}

// Q (scaled), K (rowmajor), V (Vt layout) in one launch: grid (8, 64, 3)
__global__ __launch_bounds__(256) void gemm_qkv(const unsigned short* __restrict__ A,
                                                const unsigned short* __restrict__ Wq,
                                                const unsigned short* __restrict__ Wk,
                                                const unsigned short* __restrict__ Wv,
                                                unsigned short* __restrict__ Qo,
                                                unsigned short* __restrict__ Ko,
                                                unsigned short* __restrict__ Vto) {
  const int z = blockIdx.z;
  if (z == 0)      gemm_body<3>(A, Wq, Qo,  blockIdx.x, blockIdx.y);
  else if (z == 1) gemm_body<0>(A, Wk, Ko,  blockIdx.x, blockIdx.y);
  else             gemm_body<1>(A, Wv, Vto, blockIdx.x, blockIdx.y);
}

__global__ __launch_bounds__(256) void gemm_out(const unsigned short* __restrict__ A,
                                                const unsigned short* __restrict__ Bw,
                                                float* __restrict__ Cout) {
  gemm_body<2>(A, Bw, Cout, blockIdx.x, blockIdx.y);
}

// ---------- fused causal attention v11: BARRIER-FREE, direct-L2 K/V ----------
// m169 lesson: K+V per XCD (8 bh x 512KB = 4MB) is L2-resident thanks to the XCD
// remap, so LDS staging + per-iter __syncthreads (vmcnt-drain) was pure overhead.
// K/V fragments are read straight from global (L2 hits); the only LDS use is the
// per-wave-private 2KB P repack buffer (in-wave lgkmcnt ordering, no barrier).
// Merged pass A (register-level K reuse across both q-tiles) + per-tile pass B.
__global__ __launch_bounds__(256, 4) void attn_fused(const unsigned short* __restrict__ Q,
                                                     const unsigned short* __restrict__ Kb,
                                                     const unsigned short* __restrict__ Vt,
                                                     float* __restrict__ attn,
                                                     unsigned short* __restrict__ O) {
  __shared__ char lds[8192];                   // 4 waves x 2KB P buffers only

  const int tid = threadIdx.x, lane = tid & 63, w = tid >> 6;
  const int l15 = lane & 15, l4 = lane >> 4;
  // XCD-aware remap (R7): all 16 pr-blocks of a bh co-XCD; complementary-pr pairing.
  const int F = blockIdx.x;
  const int xcd = F & 7, slot = F >> 3;
  const int g = slot >> 4, r = slot & 15;
  const int pr = ((g >> 1) & 1) ? (15 - r) : r;
  const int bh = xcd + (g << 3);
  const int b = bh >> 4, h = bh & 15;

  const int qt0 = pr, qt1 = 31 - pr;           // qt0 < qt1 always
  const int q00 = qt0 * 64 + w * 16, q01 = qt1 * 64 + w * 16;
  const int myq0 = q00 + l15, myq1 = q01 + l15;

  const size_t qk_base = ((size_t)b * 2048) * 1024 + h * 64;
  const unsigned short* Qp = Q + qk_base;
  const unsigned short* Kp = Kb + qk_base;
  const unsigned short* Vp = Vt + (size_t)bh * 64 * 2048;  // row d: d*2048 + j
  float* Ap = attn + (size_t)bh * 2048 * 2048;
  char* pbase = lds + w * 2048;

  // ---- MERGED PASS A: one sweep jt=0..qt1 computing both lsums ----
  float inv_l0, inv_l1;
  {
    short8 qf0[2], qf1[2];
    {
      const char* qrow0 = (const char*)(Qp + (size_t)myq0 * 1024);
      qf0[0] = *(const short8*)(qrow0 + (l4 * 8) * 2);
      qf0[1] = *(const short8*)(qrow0 + (32 + l4 * 8) * 2);
      const char* qrow1 = (const char*)(Qp + (size_t)myq1 * 1024);
      qf1[0] = *(const short8*)(qrow1 + (l4 * 8) * 2);
      qf1[1] = *(const short8*)(qrow1 + (32 + l4 * 8) * 2);
    }
    float lacc0[4] = {0.f, 0.f, 0.f, 0.f};
    float lacc1[4] = {0.f, 0.f, 0.f, 0.f};
    for (int jt = 0; jt <= qt1; ++jt) {
      const int jbase = jt * 64;
      const bool diag1 = (jt == qt1);
      const bool do0 = (jt <= qt0);
      const bool diag0 = (jt == qt0);
#pragma unroll
      for (int jb = 0; jb < 4; ++jb) {
        const char* krow = (const char*)(Kp + (size_t)(jbase + jb * 16 + l15) * 1024);
        short8 k0 = *(const short8*)(krow + (l4 * 8) * 2);
        short8 k1 = *(const short8*)(krow + (32 + l4 * 8) * 2);
        f32x4 a1 = {};
        a1 = MFMA16(k0, qf1[0], a1);
        a1 = MFMA16(k1, qf1[1], a1);
#pragma unroll
        for (int rr = 0; rr < 4; ++rr) {
          int j = jbase + jb * 16 + l4 * 4 + rr;
          float e = EXP2F(a1[rr]);
          lacc1[rr] += (diag1 && j > myq1) ? 0.f : e;
        }
        if (do0) {
          f32x4 a0 = {};
          a0 = MFMA16(k0, qf0[0], a0);
          a0 = MFMA16(k1, qf0[1], a0);
#pragma unroll
          for (int rr = 0; rr < 4; ++rr) {
            int j = jbase + jb * 16 + l4 * 4 + rr;
            float e = EXP2F(a0[rr]);
            lacc0[rr] += (diag0 && j > myq0) ? 0.f : e;
          }
        }
      }
    }
    float lsum0 = (lacc0[0] + lacc0[1]) + (lacc0[2] + lacc0[3]);
    lsum0 += __shfl_xor(lsum0, 16);
    lsum0 += __shfl_xor(lsum0, 32);
    float lsum1 = (lacc1[0] + lacc1[1]) + (lacc1[2] + lacc1[3]);
    lsum1 += __shfl_xor(lsum1, 16);
    lsum1 += __shfl_xor(lsum1, 32);
    inv_l0 = 1.f / lsum0;
    inv_l1 = 1.f / lsum1;
  }

  // ---- PASS B: per-tile t-loop, direct-L2 K/V, no barriers ----
  for (int t = 0; t < 2; ++t) {
    const int qt = t ? qt1 : qt0;
    const float inv_l = t ? inv_l1 : inv_l0;
    const int q0 = qt * 64 + w * 16;
    const int myq = q0 + l15;

    short8 qf[2];
    {
      const char* qrow = (const char*)(Qp + (size_t)myq * 1024);
      qf[0] = *(const short8*)(qrow + (l4 * 8) * 2);
      qf[1] = *(const short8*)(qrow + (32 + l4 * 8) * 2);
    }

    f32x4 oacc[4] = {};
    for (int jt = 0; jt <= qt; ++jt) {
      const int jbase = jt * 64;
      const bool diag = (jt == qt);
      // V loads issued early (consumed at end of iteration)
      short8 vf[8];
#pragma unroll
      for (int db = 0; db < 4; ++db) {
        const char* vrow = (const char*)(Vp + (size_t)(db * 16 + l15) * 2048);
        vf[db * 2]     = *(const short8*)(vrow + (jbase + l4 * 8) * 2);
        vf[db * 2 + 1] = *(const short8*)(vrow + (jbase + 32 + l4 * 8) * 2);
      }
      float p[16];
#pragma unroll
      for (int jb = 0; jb < 4; ++jb) {
        const char* krow = (const char*)(Kp + (size_t)(jbase + jb * 16 + l15) * 1024);
        short8 k0 = *(const short8*)(krow + (l4 * 8) * 2);
        short8 k1 = *(const short8*)(krow + (32 + l4 * 8) * 2);
        f32x4 a = {};
        a = MFMA16(k0, qf[0], a);
        a = MFMA16(k1, qf[1], a);
#pragma unroll
        for (int rr = 0; rr < 4; ++rr) {
          int j = jbase + jb * 16 + l4 * 4 + rr;
          float e = EXP2F(a[rr]) * inv_l;
          p[jb * 4 + rr] = (diag && j > myq) ? 0.f : e;
        }
      }
      // write normalized attn (fp32)
#pragma unroll
      for (int jb = 0; jb < 4; ++jb) {
        f32x4 pv = {p[jb * 4], p[jb * 4 + 1], p[jb * 4 + 2], p[jb * 4 + 3]};
        *(f32x4*)(Ap + (size_t)myq * 2048 + jbase + jb * 16 + l4 * 4) = pv;
      }
      // P -> per-wave LDS [jslot][q] (in-wave lgkmcnt ordering; no barrier)
#pragma unroll
      for (int jb = 0; jb < 4; ++jb) {
        unsigned u0 = f2bf(p[jb * 4]) | ((unsigned)f2bf(p[jb * 4 + 1]) << 16);
        unsigned u1 = f2bf(p[jb * 4 + 2]) | ((unsigned)f2bf(p[jb * 4 + 3]) << 16);
        uint2 uu; uu.x = u0; uu.y = u1;
        *(uint2*)(pbase + (jb * 2 + (l4 >> 1)) * 256 + l15 * 16 + (l4 & 1) * 8) = uu;
      }
      short8 pa0 = *(const short8*)(pbase + l4 * 256 + l15 * 16);
      short8 pa1 = *(const short8*)(pbase + (4 + l4) * 256 + l15 * 16);
#pragma unroll
      for (int db = 0; db < 4; ++db) {
        oacc[db] = MFMA16(pa0, vf[db * 2], oacc[db]);
        oacc[db] = MFMA16(pa1, vf[db * 2 + 1], oacc[db]);
      }
    }

    // zero-fill fully-masked tiles
    for (int jt = qt + 1; jt < 32; ++jt) {
      const int jbase = jt * 64;
      f32x4 z = {};
#pragma unroll
      for (int jb = 0; jb < 4; ++jb)
        *(f32x4*)(Ap + (size_t)myq * 2048 + jbase + jb * 16 + l4 * 4) = z;
    }

    // write O (bf16)
#pragma unroll
    for (int db = 0; db < 4; ++db)
#pragma unroll
      for (int rr = 0; rr < 4; ++rr) {
        int q = q0 + l4 * 4 + rr;
        int d = db * 16 + l15;
        O[((size_t)b * 2048 + q) * 1024 + h * 64 + d] = f2bf(oacc[db][rr]);
      }
  }
}

// ---------- launch ----------
extern "C" void kernel_launch(void* const* d_in, const int* in_sizes, int n_in,
                              void* d_out, int out_size, void* d_ws, size_t ws_size,
                              hipStream_t stream) {
  const float* x  = (const float*)d_in[0];
  // d_in[1] = mask (causal, recomputed analytically)
  const float* wq = (const float*)d_in[2];
  const float* wk = (const float*)d_in[3];
  const float* wv = (const float*)d_in[4];
  const float* wo = (const float*)d_in[5];

  float* out  = (float*)d_out;
  float* attn = out + (size_t)8192 * 1024;

  char* ws = (char*)d_ws;
  const size_t MB = 1 << 20;
  unsigned short* xb  = (unsigned short*)(ws);
  unsigned short* wqb = (unsigned short*)(ws + 16 * MB);
  unsigned short* wkb = (unsigned short*)(ws + 18 * MB);
  unsigned short* wvb = (unsigned short*)(ws + 20 * MB);
  unsigned short* wob = (unsigned short*)(ws + 22 * MB);
  unsigned short* Qb  = (unsigned short*)(ws + 24 * MB);
  unsigned short* Kb  = (unsigned short*)(ws + 40 * MB);
  unsigned short* Vtb = (unsigned short*)(ws + 56 * MB);
  unsigned short* Ob  = (unsigned short*)(ws + 72 * MB);

  // conversions
  cvt_f32_bf16<<<2048, 256, 0, stream>>>(x, xb, 8192 * 1024 / 4);
  cvt_w4<<<4096, 256, 0, stream>>>(wq, wk, wv, wo, wqb, wkb, wvb, wob);

  gemm_qkv<<<dim3(8, 64, 3), 256, 0, stream>>>(xb, wqb, wkb, wvb, Qb, Kb, Vtb);

  attn_fused<<<1024, 256, 0, stream>>>(Qb, Kb, Vtb, attn, Ob);

  gemm_out<<<dim3(8, 64), 256, 0, stream>>>(Ob, wob, out);
}

// Round 15
// 431.548 us; speedup vs baseline: 1.5979x; 1.5979x over previous
//
#include <hip/hip_runtime.h>

#define DEV __device__ __forceinline__

typedef __attribute__((ext_vector_type(8))) short short8;
typedef __attribute__((ext_vector_type(4))) float f32x4;

// ---------- helpers ----------
DEV unsigned short f2bf(float f) {
  unsigned u = __builtin_bit_cast(unsigned, f);
  u += 0x7fff + ((u >> 16) & 1);   // RNE
  return (unsigned short)(u >> 16);
}

DEV void gload_lds16(const void* g, void* l) {
  __builtin_amdgcn_global_load_lds(
      (const __attribute__((address_space(1))) void*)g,
      (__attribute__((address_space(3))) void*)l, 16, 0, 0);
}

#if __has_builtin(__builtin_amdgcn_exp2f)
#define EXP2F(x) __builtin_amdgcn_exp2f(x)
#else
#define EXP2F(x) exp2f(x)
#endif

#define LOG2E 1.4426950408889634f
#define QSCALE (0.125f * LOG2E)   // folded into Q projection epilogue
#define MFMA16(a, b, c) __builtin_amdgcn_mfma_f32_16x16x32_bf16((a), (b), (c), 0, 0, 0)

// ---------- fp32 -> bf16 conversion: x + all 4 weights in ONE launch ----------
// x: 2,097,152 float4; each weight: 262,144 float4. total 3,145,728 float4.
__global__ void cvt_all(const float* __restrict__ x,
                        const float* __restrict__ w0, const float* __restrict__ w1,
                        const float* __restrict__ w2, const float* __restrict__ w3,
                        unsigned short* __restrict__ xb,
                        unsigned short* __restrict__ o0, unsigned short* __restrict__ o1,
                        unsigned short* __restrict__ o2, unsigned short* __restrict__ o3) {
  int i = blockIdx.x * blockDim.x + threadIdx.x;   // 0 .. 3145728
  const float* in;
  unsigned short* out;
  int j;
  if (i < 2097152) {
    in = x; out = xb; j = i;
  } else {
    int k = i - 2097152;
    int sel = k >> 18; j = k & 0x3ffff;
    in  = sel == 0 ? w0 : sel == 1 ? w1 : sel == 2 ? w2 : w3;
    out = sel == 0 ? o0 : sel == 1 ? o1 : sel == 2 ? o2 : o3;
  }
  float4 v = ((const float4*)in)[j];
  ushort4 o;
  o.x = f2bf(v.x); o.y = f2bf(v.y); o.z = f2bf(v.z); o.w = f2bf(v.w);
  ((ushort4*)out)[j] = o;
}

// ---------- GEMM core (R10-exact, best measured): C[m,n] = sum_k A[m,k]*B[n,k] ----------
// BK=32, 2 barriers/step. R11 (BK=64+swizzle), R12 (2-phase dbuf) both regressed.
#define GK 1024
template <int MODE>  // 0: bf16 rowmajor; 1: bf16 Vt layout; 2: fp32 rowmajor; 3: bf16 rowmajor * QSCALE
DEV void gemm_body(const unsigned short* A, const unsigned short* Bw, void* Cout,
                   int bx, int by) {
  __shared__ unsigned short Ash[128 * 32];
  __shared__ unsigned short Bsh[128 * 32];
  const int tid = threadIdx.x;
  const int lane = tid & 63;
  const int w = tid >> 6;
  const int wm = w >> 1, wn = w & 1;
  const int l15 = lane & 15, l4 = lane >> 4;
  const int row0 = by * 128;
  const int col0 = bx * 128;

  f32x4 acc[4][4] = {};

  for (int kt = 0; kt < GK; kt += 32) {
    __syncthreads();
#pragma unroll
    for (int c = 0; c < 2; ++c) {
      int o = c * 4096 + tid * 16;              // linear byte offset in 8KB tile
      int ldsoff = c * 4096 + w * 1024;         // wave-uniform LDS base
      int row = o >> 6, colb = o & 63;
      gload_lds16((const char*)A + (size_t)(row0 + row) * 2048 + kt * 2 + colb,
                  (char*)Ash + ldsoff);
      gload_lds16((const char*)Bw + (size_t)(col0 + row) * 2048 + kt * 2 + colb,
                  (char*)Bsh + ldsoff);
    }
    __syncthreads();
    short8 af[4], bf[4];
#pragma unroll
    for (int m = 0; m < 4; ++m)
      af[m] = *(const short8*)((const char*)Ash + (wm * 64 + m * 16 + l15) * 64 + l4 * 16);
#pragma unroll
    for (int n = 0; n < 4; ++n)
      bf[n] = *(const short8*)((const char*)Bsh + (wn * 64 + n * 16 + l15) * 64 + l4 * 16);
#pragma unroll
    for (int m = 0; m < 4; ++m)
#pragma unroll
      for (int n = 0; n < 4; ++n)
        acc[m][n] = MFMA16(af[m], bf[n], acc[m][n]);
  }

#pragma unroll
  for (int m = 0; m < 4; ++m)
#pragma unroll
    for (int n = 0; n < 4; ++n)
#pragma unroll
      for (int r = 0; r < 4; ++r) {
        int mrow = row0 + wm * 64 + m * 16 + l4 * 4 + r;   // C/D: row=(lane>>4)*4+reg
        int ncol = col0 + wn * 64 + n * 16 + l15;          //      col=lane&15
        float v = acc[m][n][r];
        if (MODE == 0) {
          ((unsigned short*)Cout)[(size_t)mrow * 1024 + ncol] = f2bf(v);
        } else if (MODE == 1) {
          int b = mrow >> 11, s = mrow & 2047, h = ncol >> 6, d = ncol & 63;
          ((unsigned short*)Cout)[((size_t)((b * 16 + h) * 64 + d)) * 2048 + s] = f2bf(v);
        } else if (MODE == 2) {
          ((float*)Cout)[(size_t)mrow * 1024 + ncol] = v;
        } else {
          ((unsigned short*)Cout)[(size_t)mrow * 1024 + ncol] = f2bf(v * QSCALE);
        }
      }
}

// Q (scaled), K (rowmajor), V (Vt layout) in one launch: grid (8, 64, 3)
__global__ __launch_bounds__(256) void gemm_qkv(const unsigned short* __restrict__ A,
                                                const unsigned short* __restrict__ Wq,
                                                const unsigned short* __restrict__ Wk,
                                                const unsigned short* __restrict__ Wv,
                                                unsigned short* __restrict__ Qo,
                                                unsigned short* __restrict__ Ko,
                                                unsigned short* __restrict__ Vto) {
  const int z = blockIdx.z;
  if (z == 0)      gemm_body<3>(A, Wq, Qo,  blockIdx.x, blockIdx.y);
  else if (z == 1) gemm_body<0>(A, Wk, Ko,  blockIdx.x, blockIdx.y);
  else             gemm_body<1>(A, Wv, Vto, blockIdx.x, blockIdx.y);
}

__global__ __launch_bounds__(256) void gemm_out(const unsigned short* __restrict__ A,
                                                const unsigned short* __restrict__ Bw,
                                                float* __restrict__ Cout) {
  gemm_body<2>(A, Bw, Cout, blockIdx.x, blockIdx.y);
}

// ---------- fused causal attention v9 (R10-exact, best measured) ----------
// Merged pass A (one sweep jt=0..31-pr computes both q-tiles' lsums) +
// per-tile pass B t-loop. LDS staging via global_load_lds, double-buffered,
// XOR-swizzled tiles; XCD-aware remap; complementary-pr CU pairing.
// R13: setprio neutral (dropped). R14: barrier-free direct-L2 regressed 1.6x
// (attn write stream evicts K/V from L2; staging is load-once-per-block).

DEV void stage_tile(const unsigned short* src_base, size_t row_stride, int col0,
                    char* ldsbase, int tid) {
  const int w = tid >> 6;
  const int r0 = tid >> 3;
  const int c0 = (tid & 7) ^ (r0 & 7);
  gload_lds16((const char*)(src_base + (size_t)r0 * row_stride + col0 + c0 * 8),
              ldsbase + w * 1024);
  const int r1 = 32 + r0;            // (r1&7)==(r0&7) -> same swizzle
  gload_lds16((const char*)(src_base + (size_t)r1 * row_stride + col0 + c0 * 8),
              ldsbase + 4096 + w * 1024);
}

__global__ __launch_bounds__(256, 4) void attn_fused(const unsigned short* __restrict__ Q,
                                                     const unsigned short* __restrict__ Kb,
                                                     const unsigned short* __restrict__ Vt,
                                                     float* __restrict__ attn,
                                                     unsigned short* __restrict__ O) {
  __shared__ char lds[40960];

  const int tid = threadIdx.x, lane = tid & 63, w = tid >> 6;
  const int l15 = lane & 15, l4 = lane >> 4;
  const int s7 = l15 & 7;
  const int off0 = (l4 ^ s7) << 4;
  const int off1 = ((l4 + 4) ^ s7) << 4;
  const int F = blockIdx.x;
  const int xcd = F & 7, slot = F >> 3;
  const int g = slot >> 4, r = slot & 15;
  const int pr = ((g >> 1) & 1) ? (15 - r) : r;
  const int bh = xcd + (g << 3);
  const int b = bh >> 4, h = bh & 15;

  const int qt0 = pr, qt1 = 31 - pr;           // qt0 < qt1 always
  const int q00 = qt0 * 64 + w * 16, q01 = qt1 * 64 + w * 16;
  const int myq0 = q00 + l15, myq1 = q01 + l15;

  const size_t qk_base = ((size_t)b * 2048) * 1024 + h * 64;
  const unsigned short* Qp = Q + qk_base;
  const unsigned short* Kp = Kb + qk_base;
  const unsigned short* Vp = Vt + (size_t)bh * 64 * 2048;
  float* Ap = attn + (size_t)bh * 2048 * 2048;
  char* pbase = lds + 32768 + w * 2048;

  // ---- MERGED PASS A: one sweep jt=0..qt1, both lsums ----
  float inv_l0, inv_l1;
  {
    short8 qf0[2], qf1[2];
    {
      const char* qrow0 = (const char*)(Qp + (size_t)myq0 * 1024);
      qf0[0] = *(const short8*)(qrow0 + (l4 * 8) * 2);
      qf0[1] = *(const short8*)(qrow0 + (32 + l4 * 8) * 2);
      const char* qrow1 = (const char*)(Qp + (size_t)myq1 * 1024);
      qf1[0] = *(const short8*)(qrow1 + (l4 * 8) * 2);
      qf1[1] = *(const short8*)(qrow1 + (32 + l4 * 8) * 2);
    }
    float lacc0[4] = {0.f, 0.f, 0.f, 0.f};
    float lacc1[4] = {0.f, 0.f, 0.f, 0.f};
    stage_tile(Kp, 1024, 0, lds, tid);
    stage_tile(Kp + (size_t)64 * 1024, 1024, 0, lds + 8192, tid);  // qt1 >= 16
    __syncthreads();
    const int nst = (qt1 + 2) >> 1;
    for (int st = 0; st < nst; ++st) {
      char* kbb = lds + (st & 1) * 16384;
      const int jt0 = 2 * st;
      if (jt0 + 2 <= qt1) {
        char* nb = lds + ((st + 1) & 1) * 16384;
        stage_tile(Kp + (size_t)(jt0 + 2) * 64 * 1024, 1024, 0, nb, tid);
        if (jt0 + 3 <= qt1)
          stage_tile(Kp + (size_t)(jt0 + 3) * 64 * 1024, 1024, 0, nb + 8192, tid);
      }
#pragma unroll
      for (int u = 0; u < 2; ++u) {
        const int jt = jt0 + u;
        if (jt > qt1) break;
        const char* kb = kbb + u * 8192;
        const int jbase = jt * 64;
        const bool diag1 = (jt == qt1);
        const bool do0 = (jt <= qt0);
        const bool diag0 = (jt == qt0);
#pragma unroll
        for (int jb = 0; jb < 4; ++jb) {
          const char* krow = kb + (jb * 16 + l15) * 128;
          short8 k0 = *(const short8*)(krow + off0);
          short8 k1 = *(const short8*)(krow + off1);
          f32x4 a1 = {};
          a1 = MFMA16(k0, qf1[0], a1);
          a1 = MFMA16(k1, qf1[1], a1);
#pragma unroll
          for (int rr = 0; rr < 4; ++rr) {
            int j = jbase + jb * 16 + l4 * 4 + rr;
            float e = EXP2F(a1[rr]);
            lacc1[rr] += (diag1 && j > myq1) ? 0.f : e;
          }
          if (do0) {
            f32x4 a0 = {};
            a0 = MFMA16(k0, qf0[0], a0);
            a0 = MFMA16(k1, qf0[1], a0);
#pragma unroll
            for (int rr = 0; rr < 4; ++rr) {
              int j = jbase + jb * 16 + l4 * 4 + rr;
              float e = EXP2F(a0[rr]);
              lacc0[rr] += (diag0 && j > myq0) ? 0.f : e;
            }
          }
        }
      }
      __syncthreads();
    }
    float lsum0 = (lacc0[0] + lacc0[1]) + (lacc0[2] + lacc0[3]);
    lsum0 += __shfl_xor(lsum0, 16);
    lsum0 += __shfl_xor(lsum0, 32);
    float lsum1 = (lacc1[0] + lacc1[1]) + (lacc1[2] + lacc1[3]);
    lsum1 += __shfl_xor(lsum1, 16);
    lsum1 += __shfl_xor(lsum1, 32);
    inv_l0 = 1.f / lsum0;
    inv_l1 = 1.f / lsum1;
  }

  // ---- PASS B: per-tile t-loop ----
  for (int t = 0; t < 2; ++t) {
    const int qt = t ? qt1 : qt0;
    const float inv_l = t ? inv_l1 : inv_l0;
    const int q0 = qt * 64 + w * 16;
    const int myq = q0 + l15;

    short8 qf[2];
    {
      const char* qrow = (const char*)(Qp + (size_t)myq * 1024);
      qf[0] = *(const short8*)(qrow + (l4 * 8) * 2);
      qf[1] = *(const short8*)(qrow + (32 + l4 * 8) * 2);
    }

    f32x4 oacc[4] = {};
    stage_tile(Kp, 1024, 0, lds, tid);
    stage_tile(Vp, 2048, 0, lds + 16384, tid);
    __syncthreads();
    for (int jt = 0; jt <= qt; ++jt) {
      const char* kb = lds + (jt & 1) * 8192;
      const char* vb = lds + 16384 + (jt & 1) * 8192;
      if (jt < qt) {
        stage_tile(Kp + (size_t)(jt + 1) * 64 * 1024, 1024, 0,
                   lds + ((jt + 1) & 1) * 8192, tid);
        stage_tile(Vp, 2048, (jt + 1) * 64, lds + 16384 + ((jt + 1) & 1) * 8192, tid);
      }
      const int jbase = jt * 64;
      const bool diag = (jt == qt);
      float p[16];
#pragma unroll
      for (int jb = 0; jb < 4; ++jb) {
        const char* krow = kb + (jb * 16 + l15) * 128;
        short8 k0 = *(const short8*)(krow + off0);
        short8 k1 = *(const short8*)(krow + off1);
        f32x4 a = {};
        a = MFMA16(k0, qf[0], a);
        a = MFMA16(k1, qf[1], a);
#pragma unroll
        for (int rr = 0; rr < 4; ++rr) {
          int j = jbase + jb * 16 + l4 * 4 + rr;
          float e = EXP2F(a[rr]) * inv_l;
          p[jb * 4 + rr] = (diag && j > myq) ? 0.f : e;
        }
      }
      // write normalized attn (fp32)
#pragma unroll
      for (int jb = 0; jb < 4; ++jb) {
        f32x4 pv = {p[jb * 4], p[jb * 4 + 1], p[jb * 4 + 2], p[jb * 4 + 3]};
        *(f32x4*)(Ap + (size_t)myq * 2048 + jbase + jb * 16 + l4 * 4) = pv;
      }
      // P -> LDS [jslot][q]
#pragma unroll
      for (int jb = 0; jb < 4; ++jb) {
        unsigned u0 = f2bf(p[jb * 4]) | ((unsigned)f2bf(p[jb * 4 + 1]) << 16);
        unsigned u1 = f2bf(p[jb * 4 + 2]) | ((unsigned)f2bf(p[jb * 4 + 3]) << 16);
        uint2 uu; uu.x = u0; uu.y = u1;
        *(uint2*)(pbase + (jb * 2 + (l4 >> 1)) * 256 + l15 * 16 + (l4 & 1) * 8) = uu;
      }
      short8 pa0 = *(const short8*)(pbase + l4 * 256 + l15 * 16);
      short8 pa1 = *(const short8*)(pbase + (4 + l4) * 256 + l15 * 16);
#pragma unroll
      for (int db = 0; db < 4; ++db) {
        const char* vrow = vb + (db * 16 + l15) * 128;
        short8 v0 = *(const short8*)(vrow + off0);
        short8 v1 = *(const short8*)(vrow + off1);
        oacc[db] = MFMA16(pa0, v0, oacc[db]);
        oacc[db] = MFMA16(pa1, v1, oacc[db]);
      }
      __syncthreads();
    }

    // zero-fill fully-masked tiles
    for (int jt = qt + 1; jt < 32; ++jt) {
      const int jbase = jt * 64;
      f32x4 z = {};
#pragma unroll
      for (int jb = 0; jb < 4; ++jb)
        *(f32x4*)(Ap + (size_t)myq * 2048 + jbase + jb * 16 + l4 * 4) = z;
    }

    // write O (bf16)
#pragma unroll
    for (int db = 0; db < 4; ++db)
#pragma unroll
      for (int rr = 0; rr < 4; ++rr) {
        int q = q0 + l4 * 4 + rr;
        int d = db * 16 + l15;
        O[((size_t)b * 2048 + q) * 1024 + h * 64 + d] = f2bf(oacc[db][rr]);
      }
  }
}

// ---------- launch ----------
extern "C" void kernel_launch(void* const* d_in, const int* in_sizes, int n_in,
                              void* d_out, int out_size, void* d_ws, size_t ws_size,
                              hipStream_t stream) {
  const float* x  = (const float*)d_in[0];
  // d_in[1] = mask (causal, recomputed analytically)
  const float* wq = (const float*)d_in[2];
  const float* wk = (const float*)d_in[3];
  const float* wv = (const float*)d_in[4];
  const float* wo = (const float*)d_in[5];

  float* out  = (float*)d_out;
  float* attn = out + (size_t)8192 * 1024;

  char* ws = (char*)d_ws;
  const size_t MB = 1 << 20;
  unsigned short* xb  = (unsigned short*)(ws);
  unsigned short* wqb = (unsigned short*)(ws + 16 * MB);
  unsigned short* wkb = (unsigned short*)(ws + 18 * MB);
  unsigned short* wvb = (unsigned short*)(ws + 20 * MB);
  unsigned short* wob = (unsigned short*)(ws + 22 * MB);
  unsigned short* Qb  = (unsigned short*)(ws + 24 * MB);
  unsigned short* Kb  = (unsigned short*)(ws + 40 * MB);
  unsigned short* Vtb = (unsigned short*)(ws + 56 * MB);
  unsigned short* Ob  = (unsigned short*)(ws + 72 * MB);

  // all conversions in one launch (x: 2,097,152 f4 + weights: 4x262,144 f4)
  cvt_all<<<12288, 256, 0, stream>>>(x, wq, wk, wv, wo, xb, wqb, wkb, wvb, wob);

  gemm_qkv<<<dim3(8, 64, 3), 256, 0, stream>>>(xb, wqb, wkb, wvb, Qb, Kb, Vtb);

  attn_fused<<<1024, 256, 0, stream>>>(Qb, Kb, Vtb, attn, Ob);

  gemm_out<<<dim3(8, 64), 256, 0, stream>>>(Ob, wob, out);
}

// Round 16
// 418.533 us; speedup vs baseline: 1.6476x; 1.0311x over previous
//
#include <hip/hip_runtime.h>

#define DEV __device__ __forceinline__

typedef __attribute__((ext_vector_type(8))) short short8;
typedef __attribute__((ext_vector_type(4))) float f32x4;

// ---------- helpers ----------
DEV unsigned short f2bf(float f) {
  unsigned u = __builtin_bit_cast(unsigned, f);
  u += 0x7fff + ((u >> 16) & 1);   // RNE
  return (unsigned short)(u >> 16);
}

DEV void gload_lds16(const void* g, void* l) {
  __builtin_amdgcn_global_load_lds(
      (const __attribute__((address_space(1))) void*)g,
      (__attribute__((address_space(3))) void*)l, 16, 0, 0);
}

#if __has_builtin(__builtin_amdgcn_exp2f)
#define EXP2F(x) __builtin_amdgcn_exp2f(x)
#else
#define EXP2F(x) exp2f(x)
#endif

#define LOG2E 1.4426950408889634f
#define QSCALE (0.125f * LOG2E)   // folded into Q projection epilogue
#define MFMA16(a, b, c) __builtin_amdgcn_mfma_f32_16x16x32_bf16((a), (b), (c), 0, 0, 0)

// ---------- fp32 -> bf16 conversion: x + all 4 weights in ONE launch ----------
__global__ void cvt_all(const float* __restrict__ x,
                        const float* __restrict__ w0, const float* __restrict__ w1,
                        const float* __restrict__ w2, const float* __restrict__ w3,
                        unsigned short* __restrict__ xb,
                        unsigned short* __restrict__ o0, unsigned short* __restrict__ o1,
                        unsigned short* __restrict__ o2, unsigned short* __restrict__ o3) {
  int i = blockIdx.x * blockDim.x + threadIdx.x;   // 0 .. 3145728
  const float* in;
  unsigned short* out;
  int j;
  if (i < 2097152) {
    in = x; out = xb; j = i;
  } else {
    int k = i - 2097152;
    int sel = k >> 18; j = k & 0x3ffff;
    in  = sel == 0 ? w0 : sel == 1 ? w1 : sel == 2 ? w2 : w3;
    out = sel == 0 ? o0 : sel == 1 ? o1 : sel == 2 ? o2 : o3;
  }
  float4 v = ((const float4*)in)[j];
  ushort4 o;
  o.x = f2bf(v.x); o.y = f2bf(v.y); o.z = f2bf(v.z); o.w = f2bf(v.w);
  ((ushort4*)out)[j] = o;
}

// ---------- GEMM core (R10-exact, best measured): C[m,n] = sum_k A[m,k]*B[n,k] ----------
#define GK 1024
template <int MODE>  // 0: bf16 rowmajor; 1: bf16 Vt layout; 2: fp32 rowmajor; 3: bf16 rowmajor * QSCALE
DEV void gemm_body(const unsigned short* A, const unsigned short* Bw, void* Cout,
                   int bx, int by) {
  __shared__ unsigned short Ash[128 * 32];
  __shared__ unsigned short Bsh[128 * 32];
  const int tid = threadIdx.x;
  const int lane = tid & 63;
  const int w = tid >> 6;
  const int wm = w >> 1, wn = w & 1;
  const int l15 = lane & 15, l4 = lane >> 4;
  const int row0 = by * 128;
  const int col0 = bx * 128;

  f32x4 acc[4][4] = {};

  for (int kt = 0; kt < GK; kt += 32) {
    __syncthreads();
#pragma unroll
    for (int c = 0; c < 2; ++c) {
      int o = c * 4096 + tid * 16;              // linear byte offset in 8KB tile
      int ldsoff = c * 4096 + w * 1024;         // wave-uniform LDS base
      int row = o >> 6, colb = o & 63;
      gload_lds16((const char*)A + (size_t)(row0 + row) * 2048 + kt * 2 + colb,
                  (char*)Ash + ldsoff);
      gload_lds16((const char*)Bw + (size_t)(col0 + row) * 2048 + kt * 2 + colb,
                  (char*)Bsh + ldsoff);
    }
    __syncthreads();
    short8 af[4], bf[4];
#pragma unroll
    for (int m = 0; m < 4; ++m)
      af[m] = *(const short8*)((const char*)Ash + (wm * 64 + m * 16 + l15) * 64 + l4 * 16);
#pragma unroll
    for (int n = 0; n < 4; ++n)
      bf[n] = *(const short8*)((const char*)Bsh + (wn * 64 + n * 16 + l15) * 64 + l4 * 16);
#pragma unroll
    for (int m = 0; m < 4; ++m)
#pragma unroll
      for (int n = 0; n < 4; ++n)
        acc[m][n] = MFMA16(af[m], bf[n], acc[m][n]);
  }

#pragma unroll
  for (int m = 0; m < 4; ++m)
#pragma unroll
    for (int n = 0; n < 4; ++n)
#pragma unroll
      for (int r = 0; r < 4; ++r) {
        int mrow = row0 + wm * 64 + m * 16 + l4 * 4 + r;   // C/D: row=(lane>>4)*4+reg
        int ncol = col0 + wn * 64 + n * 16 + l15;          //      col=lane&15
        float v = acc[m][n][r];
        if (MODE == 0) {
          ((unsigned short*)Cout)[(size_t)mrow * 1024 + ncol] = f2bf(v);
        } else if (MODE == 1) {
          int b = mrow >> 11, s = mrow & 2047, h = ncol >> 6, d = ncol & 63;
          ((unsigned short*)Cout)[((size_t)((b * 16 + h) * 64 + d)) * 2048 + s] = f2bf(v);
        } else if (MODE == 2) {
          ((float*)Cout)[(size_t)mrow * 1024 + ncol] = v;
        } else {
          ((unsigned short*)Cout)[(size_t)mrow * 1024 + ncol] = f2bf(v * QSCALE);
        }
      }
}

// Q (scaled), K (rowmajor), V (Vt layout) in one launch: grid (8, 64, 3)
__global__ __launch_bounds__(256) void gemm_qkv(const unsigned short* __restrict__ A,
                                                const unsigned short* __restrict__ Wq,
                                                const unsigned short* __restrict__ Wk,
                                                const unsigned short* __restrict__ Wv,
                                                unsigned short* __restrict__ Qo,
                                                unsigned short* __restrict__ Ko,
                                                unsigned short* __restrict__ Vto) {
  const int z = blockIdx.z;
  if (z == 0)      gemm_body<3>(A, Wq, Qo,  blockIdx.x, blockIdx.y);
  else if (z == 1) gemm_body<0>(A, Wk, Ko,  blockIdx.x, blockIdx.y);
  else             gemm_body<1>(A, Wv, Vto, blockIdx.x, blockIdx.y);
}

__global__ __launch_bounds__(256) void gemm_out(const unsigned short* __restrict__ A,
                                                const unsigned short* __restrict__ Bw,
                                                float* __restrict__ Cout) {
  gemm_body<2>(A, Bw, Cout, blockIdx.x, blockIdx.y);
}

// ---------- fused causal attention v12 = v9 + dense zero-fill write pattern ----------
// Only change vs R15: the zero-fill (534 MB, half of attn bytes) remapped from
// 16x64B scattered segments per store to 4x256B contiguous segments
// (lane -> row q0+ri*4+(lane>>4), col (lane&15)*4). Same bytes, same count.

DEV void stage_tile(const unsigned short* src_base, size_t row_stride, int col0,
                    char* ldsbase, int tid) {
  const int w = tid >> 6;
  const int r0 = tid >> 3;
  const int c0 = (tid & 7) ^ (r0 & 7);
  gload_lds16((const char*)(src_base + (size_t)r0 * row_stride + col0 + c0 * 8),
              ldsbase + w * 1024);
  const int r1 = 32 + r0;            // (r1&7)==(r0&7) -> same swizzle
  gload_lds16((const char*)(src_base + (size_t)r1 * row_stride + col0 + c0 * 8),
              ldsbase + 4096 + w * 1024);
}

__global__ __launch_bounds__(256, 4) void attn_fused(const unsigned short* __restrict__ Q,
                                                     const unsigned short* __restrict__ Kb,
                                                     const unsigned short* __restrict__ Vt,
                                                     float* __restrict__ attn,
                                                     unsigned short* __restrict__ O) {
  __shared__ char lds[40960];

  const int tid = threadIdx.x, lane = tid & 63, w = tid >> 6;
  const int l15 = lane & 15, l4 = lane >> 4;
  const int s7 = l15 & 7;
  const int off0 = (l4 ^ s7) << 4;
  const int off1 = ((l4 + 4) ^ s7) << 4;
  const int F = blockIdx.x;
  const int xcd = F & 7, slot = F >> 3;
  const int g = slot >> 4, r = slot & 15;
  const int pr = ((g >> 1) & 1) ? (15 - r) : r;
  const int bh = xcd + (g << 3);
  const int b = bh >> 4, h = bh & 15;

  const int qt0 = pr, qt1 = 31 - pr;           // qt0 < qt1 always
  const int q00 = qt0 * 64 + w * 16, q01 = qt1 * 64 + w * 16;
  const int myq0 = q00 + l15, myq1 = q01 + l15;

  const size_t qk_base = ((size_t)b * 2048) * 1024 + h * 64;
  const unsigned short* Qp = Q + qk_base;
  const unsigned short* Kp = Kb + qk_base;
  const unsigned short* Vp = Vt + (size_t)bh * 64 * 2048;
  float* Ap = attn + (size_t)bh * 2048 * 2048;
  char* pbase = lds + 32768 + w * 2048;

  // ---- MERGED PASS A: one sweep jt=0..qt1, both lsums ----
  float inv_l0, inv_l1;
  {
    short8 qf0[2], qf1[2];
    {
      const char* qrow0 = (const char*)(Qp + (size_t)myq0 * 1024);
      qf0[0] = *(const short8*)(qrow0 + (l4 * 8) * 2);
      qf0[1] = *(const short8*)(qrow0 + (32 + l4 * 8) * 2);
      const char* qrow1 = (const char*)(Qp + (size_t)myq1 * 1024);
      qf1[0] = *(const short8*)(qrow1 + (l4 * 8) * 2);
      qf1[1] = *(const short8*)(qrow1 + (32 + l4 * 8) * 2);
    }
    float lacc0[4] = {0.f, 0.f, 0.f, 0.f};
    float lacc1[4] = {0.f, 0.f, 0.f, 0.f};
    stage_tile(Kp, 1024, 0, lds, tid);
    stage_tile(Kp + (size_t)64 * 1024, 1024, 0, lds + 8192, tid);  // qt1 >= 16
    __syncthreads();
    const int nst = (qt1 + 2) >> 1;
    for (int st = 0; st < nst; ++st) {
      char* kbb = lds + (st & 1) * 16384;
      const int jt0 = 2 * st;
      if (jt0 + 2 <= qt1) {
        char* nb = lds + ((st + 1) & 1) * 16384;
        stage_tile(Kp + (size_t)(jt0 + 2) * 64 * 1024, 1024, 0, nb, tid);
        if (jt0 + 3 <= qt1)
          stage_tile(Kp + (size_t)(jt0 + 3) * 64 * 1024, 1024, 0, nb + 8192, tid);
      }
#pragma unroll
      for (int u = 0; u < 2; ++u) {
        const int jt = jt0 + u;
        if (jt > qt1) break;
        const char* kb = kbb + u * 8192;
        const int jbase = jt * 64;
        const bool diag1 = (jt == qt1);
        const bool do0 = (jt <= qt0);
        const bool diag0 = (jt == qt0);
#pragma unroll
        for (int jb = 0; jb < 4; ++jb) {
          const char* krow = kb + (jb * 16 + l15) * 128;
          short8 k0 = *(const short8*)(krow + off0);
          short8 k1 = *(const short8*)(krow + off1);
          f32x4 a1 = {};
          a1 = MFMA16(k0, qf1[0], a1);
          a1 = MFMA16(k1, qf1[1], a1);
#pragma unroll
          for (int rr = 0; rr < 4; ++rr) {
            int j = jbase + jb * 16 + l4 * 4 + rr;
            float e = EXP2F(a1[rr]);
            lacc1[rr] += (diag1 && j > myq1) ? 0.f : e;
          }
          if (do0) {
            f32x4 a0 = {};
            a0 = MFMA16(k0, qf0[0], a0);
            a0 = MFMA16(k1, qf0[1], a0);
#pragma unroll
            for (int rr = 0; rr < 4; ++rr) {
              int j = jbase + jb * 16 + l4 * 4 + rr;
              float e = EXP2F(a0[rr]);
              lacc0[rr] += (diag0 && j > myq0) ? 0.f : e;
            }
          }
        }
      }
      __syncthreads();
    }
    float lsum0 = (lacc0[0] + lacc0[1]) + (lacc0[2] + lacc0[3]);
    lsum0 += __shfl_xor(lsum0, 16);
    lsum0 += __shfl_xor(lsum0, 32);
    float lsum1 = (lacc1[0] + lacc1[1]) + (lacc1[2] + lacc1[3]);
    lsum1 += __shfl_xor(lsum1, 16);
    lsum1 += __shfl_xor(lsum1, 32);
    inv_l0 = 1.f / lsum0;
    inv_l1 = 1.f / lsum1;
  }

  // ---- PASS B: per-tile t-loop ----
  for (int t = 0; t < 2; ++t) {
    const int qt = t ? qt1 : qt0;
    const float inv_l = t ? inv_l1 : inv_l0;
    const int q0 = qt * 64 + w * 16;
    const int myq = q0 + l15;

    short8 qf[2];
    {
      const char* qrow = (const char*)(Qp + (size_t)myq * 1024);
      qf[0] = *(const short8*)(qrow + (l4 * 8) * 2);
      qf[1] = *(const short8*)(qrow + (32 + l4 * 8) * 2);
    }

    f32x4 oacc[4] = {};
    stage_tile(Kp, 1024, 0, lds, tid);
    stage_tile(Vp, 2048, 0, lds + 16384, tid);
    __syncthreads();
    for (int jt = 0; jt <= qt; ++jt) {
      const char* kb = lds + (jt & 1) * 8192;
      const char* vb = lds + 16384 + (jt & 1) * 8192;
      if (jt < qt) {
        stage_tile(Kp + (size_t)(jt + 1) * 64 * 1024, 1024, 0,
                   lds + ((jt + 1) & 1) * 8192, tid);
        stage_tile(Vp, 2048, (jt + 1) * 64, lds + 16384 + ((jt + 1) & 1) * 8192, tid);
      }
      const int jbase = jt * 64;
      const bool diag = (jt == qt);
      float p[16];
#pragma unroll
      for (int jb = 0; jb < 4; ++jb) {
        const char* krow = kb + (jb * 16 + l15) * 128;
        short8 k0 = *(const short8*)(krow + off0);
        short8 k1 = *(const short8*)(krow + off1);
        f32x4 a = {};
        a = MFMA16(k0, qf[0], a);
        a = MFMA16(k1, qf[1], a);
#pragma unroll
        for (int rr = 0; rr < 4; ++rr) {
          int j = jbase + jb * 16 + l4 * 4 + rr;
          float e = EXP2F(a[rr]) * inv_l;
          p[jb * 4 + rr] = (diag && j > myq) ? 0.f : e;
        }
      }
      // write normalized attn (fp32)
#pragma unroll
      for (int jb = 0; jb < 4; ++jb) {
        f32x4 pv = {p[jb * 4], p[jb * 4 + 1], p[jb * 4 + 2], p[jb * 4 + 3]};
        *(f32x4*)(Ap + (size_t)myq * 2048 + jbase + jb * 16 + l4 * 4) = pv;
      }
      // P -> LDS [jslot][q]
#pragma unroll
      for (int jb = 0; jb < 4; ++jb) {
        unsigned u0 = f2bf(p[jb * 4]) | ((unsigned)f2bf(p[jb * 4 + 1]) << 16);
        unsigned u1 = f2bf(p[jb * 4 + 2]) | ((unsigned)f2bf(p[jb * 4 + 3]) << 16);
        uint2 uu; uu.x = u0; uu.y = u1;
        *(uint2*)(pbase + (jb * 2 + (l4 >> 1)) * 256 + l15 * 16 + (l4 & 1) * 8) = uu;
      }
      short8 pa0 = *(const short8*)(pbase + l4 * 256 + l15 * 16);
      short8 pa1 = *(const short8*)(pbase + (4 + l4) * 256 + l15 * 16);
#pragma unroll
      for (int db = 0; db < 4; ++db) {
        const char* vrow = vb + (db * 16 + l15) * 128;
        short8 v0 = *(const short8*)(vrow + off0);
        short8 v1 = *(const short8*)(vrow + off1);
        oacc[db] = MFMA16(pa0, v0, oacc[db]);
        oacc[db] = MFMA16(pa1, v1, oacc[db]);
      }
      __syncthreads();
    }

    // zero-fill fully-masked tiles (DENSE pattern: 4x256B segments per store)
    {
      f32x4 z = {};
      for (int jt = qt + 1; jt < 32; ++jt) {
        const int jbase = jt * 64;
#pragma unroll
        for (int ri = 0; ri < 4; ++ri) {
          int row = q0 + ri * 4 + l4;           // lanes 0-15 contiguous in-row
          *(f32x4*)(Ap + (size_t)row * 2048 + jbase + l15 * 4) = z;
        }
      }
    }

    // write O (bf16)
#pragma unroll
    for (int db = 0; db < 4; ++db)
#pragma unroll
      for (int rr = 0; rr < 4; ++rr) {
        int q = q0 + l4 * 4 + rr;
        int d = db * 16 + l15;
        O[((size_t)b * 2048 + q) * 1024 + h * 64 + d] = f2bf(oacc[db][rr]);
      }
  }
}

// ---------- launch ----------
extern "C" void kernel_launch(void* const* d_in, const int* in_sizes, int n_in,
                              void* d_out, int out_size, void* d_ws, size_t ws_size,
                              hipStream_t stream) {
  const float* x  = (const float*)d_in[0];
  // d_in[1] = mask (causal, recomputed analytically)
  const float* wq = (const float*)d_in[2];
  const float* wk = (const float*)d_in[3];
  const float* wv = (const float*)d_in[4];
  const float* wo = (const float*)d_in[5];

  float* out  = (float*)d_out;
  float* attn = out + (size_t)8192 * 1024;

  char* ws = (char*)d_ws;
  const size_t MB = 1 << 20;
  unsigned short* xb  = (unsigned short*)(ws);
  unsigned short* wqb = (unsigned short*)(ws + 16 * MB);
  unsigned short* wkb = (unsigned short*)(ws + 18 * MB);
  unsigned short* wvb = (unsigned short*)(ws + 20 * MB);
  unsigned short* wob = (unsigned short*)(ws + 22 * MB);
  unsigned short* Qb  = (unsigned short*)(ws + 24 * MB);
  unsigned short* Kb  = (unsigned short*)(ws + 40 * MB);
  unsigned short* Vtb = (unsigned short*)(ws + 56 * MB);
  unsigned short* Ob  = (unsigned short*)(ws + 72 * MB);

  // all conversions in one launch (x: 2,097,152 f4 + weights: 4x262,144 f4)
  cvt_all<<<12288, 256, 0, stream>>>(x, wq, wk, wv, wo, xb, wqb, wkb, wvb, wob);

  gemm_qkv<<<dim3(8, 64, 3), 256, 0, stream>>>(xb, wqb, wkb, wvb, Qb, Kb, Vtb);

  attn_fused<<<1024, 256, 0, stream>>>(Qb, Kb, Vtb, attn, Ob);

  gemm_out<<<dim3(8, 64), 256, 0, stream>>>(Ob, wob, out);
}

// Round 17
// 396.825 us; speedup vs baseline: 1.7377x; 1.0547x over previous
//
#include <hip/hip_runtime.h>

#define DEV __device__ __forceinline__

typedef __attribute__((ext_vector_type(8))) short short8;
typedef __attribute__((ext_vector_type(4))) float f32x4;

// ---------- helpers ----------
DEV unsigned short f2bf(float f) {
  unsigned u = __builtin_bit_cast(unsigned, f);
  u += 0x7fff + ((u >> 16) & 1);   // RNE
  return (unsigned short)(u >> 16);
}

DEV void gload_lds16(const void* g, void* l) {
  __builtin_amdgcn_global_load_lds(
      (const __attribute__((address_space(1))) void*)g,
      (__attribute__((address_space(3))) void*)l, 16, 0, 0);
}

#if __has_builtin(__builtin_amdgcn_exp2f)
#define EXP2F(x) __builtin_amdgcn_exp2f(x)
#else
#define EXP2F(x) exp2f(x)
#endif

#define LOG2E 1.4426950408889634f
#define QSCALE (0.125f * LOG2E)   // folded into Q projection epilogue
#define MFMA16(a, b, c) __builtin_amdgcn_mfma_f32_16x16x32_bf16((a), (b), (c), 0, 0, 0)

// ---------- fp32 -> bf16 conversion: x + all 4 weights in ONE launch ----------
__global__ void cvt_all(const float* __restrict__ x,
                        const float* __restrict__ w0, const float* __restrict__ w1,
                        const float* __restrict__ w2, const float* __restrict__ w3,
                        unsigned short* __restrict__ xb,
                        unsigned short* __restrict__ o0, unsigned short* __restrict__ o1,
                        unsigned short* __restrict__ o2, unsigned short* __restrict__ o3) {
  int i = blockIdx.x * blockDim.x + threadIdx.x;   // 0 .. 3145728
  const float* in;
  unsigned short* out;
  int j;
  if (i < 2097152) {
    in = x; out = xb; j = i;
  } else {
    int k = i - 2097152;
    int sel = k >> 18; j = k & 0x3ffff;
    in  = sel == 0 ? w0 : sel == 1 ? w1 : sel == 2 ? w2 : w3;
    out = sel == 0 ? o0 : sel == 1 ? o1 : sel == 2 ? o2 : o3;
  }
  float4 v = ((const float4*)in)[j];
  ushort4 o;
  o.x = f2bf(v.x); o.y = f2bf(v.y); o.z = f2bf(v.z); o.w = f2bf(v.w);
  ((ushort4*)out)[j] = o;
}

// ---------- GEMM core (R10-exact, best measured): C[m,n] = sum_k A[m,k]*B[n,k] ----------
#define GK 1024
template <int MODE>  // 0: bf16 rowmajor; 1: bf16 Vt layout; 2: fp32 rowmajor; 3: bf16 rowmajor * QSCALE
DEV void gemm_body(const unsigned short* A, const unsigned short* Bw, void* Cout,
                   int bx, int by) {
  __shared__ unsigned short Ash[128 * 32];
  __shared__ unsigned short Bsh[128 * 32];
  const int tid = threadIdx.x;
  const int lane = tid & 63;
  const int w = tid >> 6;
  const int wm = w >> 1, wn = w & 1;
  const int l15 = lane & 15, l4 = lane >> 4;
  const int row0 = by * 128;
  const int col0 = bx * 128;

  f32x4 acc[4][4] = {};

  for (int kt = 0; kt < GK; kt += 32) {
    __syncthreads();
#pragma unroll
    for (int c = 0; c < 2; ++c) {
      int o = c * 4096 + tid * 16;              // linear byte offset in 8KB tile
      int ldsoff = c * 4096 + w * 1024;         // wave-uniform LDS base
      int row = o >> 6, colb = o & 63;
      gload_lds16((const char*)A + (size_t)(row0 + row) * 2048 + kt * 2 + colb,
                  (char*)Ash + ldsoff);
      gload_lds16((const char*)Bw + (size_t)(col0 + row) * 2048 + kt * 2 + colb,
                  (char*)Bsh + ldsoff);
    }
    __syncthreads();
    short8 af[4], bf[4];
#pragma unroll
    for (int m = 0; m < 4; ++m)
      af[m] = *(const short8*)((const char*)Ash + (wm * 64 + m * 16 + l15) * 64 + l4 * 16);
#pragma unroll
    for (int n = 0; n < 4; ++n)
      bf[n] = *(const short8*)((const char*)Bsh + (wn * 64 + n * 16 + l15) * 64 + l4 * 16);
#pragma unroll
    for (int m = 0; m < 4; ++m)
#pragma unroll
      for (int n = 0; n < 4; ++n)
        acc[m][n] = MFMA16(af[m], bf[n], acc[m][n]);
  }

#pragma unroll
  for (int m = 0; m < 4; ++m)
#pragma unroll
    for (int n = 0; n < 4; ++n)
#pragma unroll
      for (int r = 0; r < 4; ++r) {
        int mrow = row0 + wm * 64 + m * 16 + l4 * 4 + r;   // C/D: row=(lane>>4)*4+reg
        int ncol = col0 + wn * 64 + n * 16 + l15;          //      col=lane&15
        float v = acc[m][n][r];
        if (MODE == 0) {
          ((unsigned short*)Cout)[(size_t)mrow * 1024 + ncol] = f2bf(v);
        } else if (MODE == 1) {
          int b = mrow >> 11, s = mrow & 2047, h = ncol >> 6, d = ncol & 63;
          ((unsigned short*)Cout)[((size_t)((b * 16 + h) * 64 + d)) * 2048 + s] = f2bf(v);
        } else if (MODE == 2) {
          ((float*)Cout)[(size_t)mrow * 1024 + ncol] = v;
        } else {
          ((unsigned short*)Cout)[(size_t)mrow * 1024 + ncol] = f2bf(v * QSCALE);
        }
      }
}

// Q (scaled), K (rowmajor), V (Vt layout) in one launch: grid (8, 64, 3)
__global__ __launch_bounds__(256) void gemm_qkv(const unsigned short* __restrict__ A,
                                                const unsigned short* __restrict__ Wq,
                                                const unsigned short* __restrict__ Wk,
                                                const unsigned short* __restrict__ Wv,
                                                unsigned short* __restrict__ Qo,
                                                unsigned short* __restrict__ Ko,
                                                unsigned short* __restrict__ Vto) {
  const int z = blockIdx.z;
  if (z == 0)      gemm_body<3>(A, Wq, Qo,  blockIdx.x, blockIdx.y);
  else if (z == 1) gemm_body<0>(A, Wk, Ko,  blockIdx.x, blockIdx.y);
  else             gemm_body<1>(A, Wv, Vto, blockIdx.x, blockIdx.y);
}

__global__ __launch_bounds__(256) void gemm_out(const unsigned short* __restrict__ A,
                                                const unsigned short* __restrict__ Bw,
                                                float* __restrict__ Cout) {
  gemm_body<2>(A, Bw, Cout, blockIdx.x, blockIdx.y);
}

// ---------- fused causal attention v13 = v12 + dense NORMALIZED writes via LDS ----------
// P_lds relayout to q-major 128B rows with slot-XOR swizzle:
//   byte(q, j) = q*128 + ((j>>3) ^ (q&7))*16 + ((j>>2)&1)*8   (4-bf16 granules)
// Writer (q=l15, j=jb*16+l4*4): 4-way banks (same as before).
// PV frag read (q=l15, slot=l4 / 4+l4): 2-way (free).
// NEW dense attn write: lane reads P[qrow=ri*4+l4][j=l15*4..+3] back from LDS
// (4-way on 8B reads), widens bf16->fp32, stores 4x256B contiguous segments --
// same dense pattern that won for zero-fill (R16). attn is bf16-rounded
// (identical values PV consumes); error << threshold.

DEV void stage_tile(const unsigned short* src_base, size_t row_stride, int col0,
                    char* ldsbase, int tid) {
  const int w = tid >> 6;
  const int r0 = tid >> 3;
  const int c0 = (tid & 7) ^ (r0 & 7);
  gload_lds16((const char*)(src_base + (size_t)r0 * row_stride + col0 + c0 * 8),
              ldsbase + w * 1024);
  const int r1 = 32 + r0;            // (r1&7)==(r0&7) -> same swizzle
  gload_lds16((const char*)(src_base + (size_t)r1 * row_stride + col0 + c0 * 8),
              ldsbase + 4096 + w * 1024);
}

__global__ __launch_bounds__(256, 4) void attn_fused(const unsigned short* __restrict__ Q,
                                                     const unsigned short* __restrict__ Kb,
                                                     const unsigned short* __restrict__ Vt,
                                                     float* __restrict__ attn,
                                                     unsigned short* __restrict__ O) {
  __shared__ char lds[40960];

  const int tid = threadIdx.x, lane = tid & 63, w = tid >> 6;
  const int l15 = lane & 15, l4 = lane >> 4;
  const int s7 = l15 & 7;
  const int off0 = (l4 ^ s7) << 4;
  const int off1 = ((l4 + 4) ^ s7) << 4;
  const int F = blockIdx.x;
  const int xcd = F & 7, slot = F >> 3;
  const int g = slot >> 4, r = slot & 15;
  const int pr = ((g >> 1) & 1) ? (15 - r) : r;
  const int bh = xcd + (g << 3);
  const int b = bh >> 4, h = bh & 15;

  const int qt0 = pr, qt1 = 31 - pr;           // qt0 < qt1 always
  const int q00 = qt0 * 64 + w * 16, q01 = qt1 * 64 + w * 16;
  const int myq0 = q00 + l15, myq1 = q01 + l15;

  const size_t qk_base = ((size_t)b * 2048) * 1024 + h * 64;
  const unsigned short* Qp = Q + qk_base;
  const unsigned short* Kp = Kb + qk_base;
  const unsigned short* Vp = Vt + (size_t)bh * 64 * 2048;
  float* Ap = attn + (size_t)bh * 2048 * 2048;
  char* pbase = lds + 32768 + w * 2048;

  // ---- MERGED PASS A: one sweep jt=0..qt1, both lsums ----
  float inv_l0, inv_l1;
  {
    short8 qf0[2], qf1[2];
    {
      const char* qrow0 = (const char*)(Qp + (size_t)myq0 * 1024);
      qf0[0] = *(const short8*)(qrow0 + (l4 * 8) * 2);
      qf0[1] = *(const short8*)(qrow0 + (32 + l4 * 8) * 2);
      const char* qrow1 = (const char*)(Qp + (size_t)myq1 * 1024);
      qf1[0] = *(const short8*)(qrow1 + (l4 * 8) * 2);
      qf1[1] = *(const short8*)(qrow1 + (32 + l4 * 8) * 2);
    }
    float lacc0[4] = {0.f, 0.f, 0.f, 0.f};
    float lacc1[4] = {0.f, 0.f, 0.f, 0.f};
    stage_tile(Kp, 1024, 0, lds, tid);
    stage_tile(Kp + (size_t)64 * 1024, 1024, 0, lds + 8192, tid);  // qt1 >= 16
    __syncthreads();
    const int nst = (qt1 + 2) >> 1;
    for (int st = 0; st < nst; ++st) {
      char* kbb = lds + (st & 1) * 16384;
      const int jt0 = 2 * st;
      if (jt0 + 2 <= qt1) {
        char* nb = lds + ((st + 1) & 1) * 16384;
        stage_tile(Kp + (size_t)(jt0 + 2) * 64 * 1024, 1024, 0, nb, tid);
        if (jt0 + 3 <= qt1)
          stage_tile(Kp + (size_t)(jt0 + 3) * 64 * 1024, 1024, 0, nb + 8192, tid);
      }
#pragma unroll
      for (int u = 0; u < 2; ++u) {
        const int jt = jt0 + u;
        if (jt > qt1) break;
        const char* kb = kbb + u * 8192;
        const int jbase = jt * 64;
        const bool diag1 = (jt == qt1);
        const bool do0 = (jt <= qt0);
        const bool diag0 = (jt == qt0);
#pragma unroll
        for (int jb = 0; jb < 4; ++jb) {
          const char* krow = kb + (jb * 16 + l15) * 128;
          short8 k0 = *(const short8*)(krow + off0);
          short8 k1 = *(const short8*)(krow + off1);
          f32x4 a1 = {};
          a1 = MFMA16(k0, qf1[0], a1);
          a1 = MFMA16(k1, qf1[1], a1);
#pragma unroll
          for (int rr = 0; rr < 4; ++rr) {
            int j = jbase + jb * 16 + l4 * 4 + rr;
            float e = EXP2F(a1[rr]);
            lacc1[rr] += (diag1 && j > myq1) ? 0.f : e;
          }
          if (do0) {
            f32x4 a0 = {};
            a0 = MFMA16(k0, qf0[0], a0);
            a0 = MFMA16(k1, qf0[1], a0);
#pragma unroll
            for (int rr = 0; rr < 4; ++rr) {
              int j = jbase + jb * 16 + l4 * 4 + rr;
              float e = EXP2F(a0[rr]);
              lacc0[rr] += (diag0 && j > myq0) ? 0.f : e;
            }
          }
        }
      }
      __syncthreads();
    }
    float lsum0 = (lacc0[0] + lacc0[1]) + (lacc0[2] + lacc0[3]);
    lsum0 += __shfl_xor(lsum0, 16);
    lsum0 += __shfl_xor(lsum0, 32);
    float lsum1 = (lacc1[0] + lacc1[1]) + (lacc1[2] + lacc1[3]);
    lsum1 += __shfl_xor(lsum1, 16);
    lsum1 += __shfl_xor(lsum1, 32);
    inv_l0 = 1.f / lsum0;
    inv_l1 = 1.f / lsum1;
  }

  // ---- PASS B: per-tile t-loop ----
  for (int t = 0; t < 2; ++t) {
    const int qt = t ? qt1 : qt0;
    const float inv_l = t ? inv_l1 : inv_l0;
    const int q0 = qt * 64 + w * 16;
    const int myq = q0 + l15;

    short8 qf[2];
    {
      const char* qrow = (const char*)(Qp + (size_t)myq * 1024);
      qf[0] = *(const short8*)(qrow + (l4 * 8) * 2);
      qf[1] = *(const short8*)(qrow + (32 + l4 * 8) * 2);
    }

    f32x4 oacc[4] = {};
    stage_tile(Kp, 1024, 0, lds, tid);
    stage_tile(Vp, 2048, 0, lds + 16384, tid);
    __syncthreads();
    for (int jt = 0; jt <= qt; ++jt) {
      const char* kb = lds + (jt & 1) * 8192;
      const char* vb = lds + 16384 + (jt & 1) * 8192;
      if (jt < qt) {
        stage_tile(Kp + (size_t)(jt + 1) * 64 * 1024, 1024, 0,
                   lds + ((jt + 1) & 1) * 8192, tid);
        stage_tile(Vp, 2048, (jt + 1) * 64, lds + 16384 + ((jt + 1) & 1) * 8192, tid);
      }
      const int jbase = jt * 64;
      const bool diag = (jt == qt);
      float p[16];
#pragma unroll
      for (int jb = 0; jb < 4; ++jb) {
        const char* krow = kb + (jb * 16 + l15) * 128;
        short8 k0 = *(const short8*)(krow + off0);
        short8 k1 = *(const short8*)(krow + off1);
        f32x4 a = {};
        a = MFMA16(k0, qf[0], a);
        a = MFMA16(k1, qf[1], a);
#pragma unroll
        for (int rr = 0; rr < 4; ++rr) {
          int j = jbase + jb * 16 + l4 * 4 + rr;
          float e = EXP2F(a[rr]) * inv_l;
          p[jb * 4 + rr] = (diag && j > myq) ? 0.f : e;
        }
      }
      // P -> LDS, q-major swizzled: byte(q=l15, slot=jb*2+(l4>>1), t=l4&1)
#pragma unroll
      for (int jb = 0; jb < 4; ++jb) {
        unsigned u0 = f2bf(p[jb * 4]) | ((unsigned)f2bf(p[jb * 4 + 1]) << 16);
        unsigned u1 = f2bf(p[jb * 4 + 2]) | ((unsigned)f2bf(p[jb * 4 + 3]) << 16);
        uint2 uu; uu.x = u0; uu.y = u1;
        int slotw = (jb * 2 + (l4 >> 1)) ^ s7;
        *(uint2*)(pbase + l15 * 128 + slotw * 16 + (l4 & 1) * 8) = uu;
      }
      // dense attn write: lane -> rows q0+ri*4+l4, cols jbase+l15*4 (4x256B segs)
#pragma unroll
      for (int ri = 0; ri < 4; ++ri) {
        int qrow = ri * 4 + l4;
        uint2 uu = *(const uint2*)(pbase + qrow * 128 +
                                   (((l15 >> 1) ^ (qrow & 7)) << 4) + (l15 & 1) * 8);
        f32x4 pv;
        pv[0] = __builtin_bit_cast(float, uu.x << 16);
        pv[1] = __builtin_bit_cast(float, uu.x & 0xffff0000u);
        pv[2] = __builtin_bit_cast(float, uu.y << 16);
        pv[3] = __builtin_bit_cast(float, uu.y & 0xffff0000u);
        *(f32x4*)(Ap + (size_t)(q0 + qrow) * 2048 + jbase + l15 * 4) = pv;
      }
      // PV frag reads: q=l15, slots l4 and 4+l4 (swizzled; 2-way banks)
      short8 pa0 = *(const short8*)(pbase + l15 * 128 + ((l4 ^ s7) << 4));
      short8 pa1 = *(const short8*)(pbase + l15 * 128 + (((4 + l4) ^ s7) << 4));
#pragma unroll
      for (int db = 0; db < 4; ++db) {
        const char* vrow = vb + (db * 16 + l15) * 128;
        short8 v0 = *(const short8*)(vrow + off0);
        short8 v1 = *(const short8*)(vrow + off1);
        oacc[db] = MFMA16(pa0, v0, oacc[db]);
        oacc[db] = MFMA16(pa1, v1, oacc[db]);
      }
      __syncthreads();
    }

    // zero-fill fully-masked tiles (dense pattern, R16-proven)
    {
      f32x4 z = {};
      for (int jt = qt + 1; jt < 32; ++jt) {
        const int jbase = jt * 64;
#pragma unroll
        for (int ri = 0; ri < 4; ++ri) {
          int row = q0 + ri * 4 + l4;           // lanes 0-15 contiguous in-row
          *(f32x4*)(Ap + (size_t)row * 2048 + jbase + l15 * 4) = z;
        }
      }
    }

    // write O (bf16)
#pragma unroll
    for (int db = 0; db < 4; ++db)
#pragma unroll
      for (int rr = 0; rr < 4; ++rr) {
        int q = q0 + l4 * 4 + rr;
        int d = db * 16 + l15;
        O[((size_t)b * 2048 + q) * 1024 + h * 64 + d] = f2bf(oacc[db][rr]);
      }
  }
}

// ---------- launch ----------
extern "C" void kernel_launch(void* const* d_in, const int* in_sizes, int n_in,
                              void* d_out, int out_size, void* d_ws, size_t ws_size,
                              hipStream_t stream) {
  const float* x  = (const float*)d_in[0];
  // d_in[1] = mask (causal, recomputed analytically)
  const float* wq = (const float*)d_in[2];
  const float* wk = (const float*)d_in[3];
  const float* wv = (const float*)d_in[4];
  const float* wo = (const float*)d_in[5];

  float* out  = (float*)d_out;
  float* attn = out + (size_t)8192 * 1024;

  char* ws = (char*)d_ws;
  const size_t MB = 1 << 20;
  unsigned short* xb  = (unsigned short*)(ws);
  unsigned short* wqb = (unsigned short*)(ws + 16 * MB);
  unsigned short* wkb = (unsigned short*)(ws + 18 * MB);
  unsigned short* wvb = (unsigned short*)(ws + 20 * MB);
  unsigned short* wob = (unsigned short*)(ws + 22 * MB);
  unsigned short* Qb  = (unsigned short*)(ws + 24 * MB);
  unsigned short* Kb  = (unsigned short*)(ws + 40 * MB);
  unsigned short* Vtb = (unsigned short*)(ws + 56 * MB);
  unsigned short* Ob  = (unsigned short*)(ws + 72 * MB);

  // all conversions in one launch (x: 2,097,152 f4 + weights: 4x262,144 f4)
  cvt_all<<<12288, 256, 0, stream>>>(x, wq, wk, wv, wo, xb, wqb, wkb, wvb, wob);

  gemm_qkv<<<dim3(8, 64, 3), 256, 0, stream>>>(xb, wqb, wkb, wvb, Qb, Kb, Vtb);

  attn_fused<<<1024, 256, 0, stream>>>(Qb, Kb, Vtb, attn, Ob);

  gemm_out<<<dim3(8, 64), 256, 0, stream>>>(Ob, wob, out);
}